// Round 3
// baseline (444.474 us; speedup 1.0000x reference)
//
#include <hip/hip_runtime.h>
#include <hip/hip_bf16.h>

#define Bn 32
#define Ln 2048
#define Dn 768
#define Hn 512
#define Mn (Bn*Ln)
#define EPSC 1e-5f

// ws float-offset layout
#define OFF_S1   0        // [512] masked sum(h)
#define OFF_S2   512      // [512] masked sum(h^2)
#define OFF_SC   1024     // [512] istd*gamma
#define OFF_SH   1536     // [512] beta - mean*sc
#define OFF_CNT  2048     // [32]
#define OFF_PH   2304     // [32*512] pooled relu(BN(h)) sums (direct-stored)
#define ZERO_N   1024     // only S1,S2 need zeroing
#define OFF_W1T_BYTES  131072            // bf16 W1^T [512][768]
#define OFF_H_BYTES    1048576           // tiled bf16 h buffer, 64 MB

#define BM 128
#define BN2 256
#define BK 64
#define LDK 72   // padded LDS k-stride (bf16): 144 B -> 2-way banks, 16B-aligned

typedef __attribute__((ext_vector_type(8))) short bf16x8;
typedef __attribute__((ext_vector_type(4))) float f32x4;

static __device__ __forceinline__ unsigned short f2bf(float x) {
  __hip_bfloat16 h = __float2bfloat16(x);
  return *reinterpret_cast<unsigned short*>(&h);
}
static __device__ __forceinline__ float bf2f(unsigned short u) {
  return __uint_as_float(((unsigned int)u) << 16);
}

__global__ void zero_kernel(float* __restrict__ p, int n) {
  int i = blockIdx.x * 256 + threadIdx.x;
  if (i < n) p[i] = 0.f;
}

__global__ void count_kernel(const int* __restrict__ mask, float* __restrict__ cnt) {
  __shared__ int red[256];
  int b = blockIdx.x, t = threadIdx.x;
  int s = 0;
#pragma unroll
  for (int i = 0; i < 8; i++) s += mask[b * Ln + i * 256 + t];
  red[t] = s;
  __syncthreads();
  for (int off = 128; off > 0; off >>= 1) {
    if (t < off) red[t] += red[t + off];
    __syncthreads();
  }
  if (t == 0) cnt[b] = (float)red[0];
}

// W1 [768][512] fp32 -> W1t [512][768] bf16
__global__ __launch_bounds__(256) void transpose_w1(
    const float* __restrict__ W1, unsigned short* __restrict__ W1t) {
  __shared__ float tile[32][33];
  int kx = blockIdx.x * 32;
  int nx = blockIdx.y * 32;
  int tx = threadIdx.x & 31, ty = threadIdx.x >> 5;
#pragma unroll
  for (int i = 0; i < 32; i += 8)
    tile[ty + i][tx] = W1[(size_t)(kx + ty + i) * Hn + nx + tx];
  __syncthreads();
#pragma unroll
  for (int i = 0; i < 32; i += 8)
    W1t[(size_t)(nx + ty + i) * Dn + kx + tx] = f2bf(tile[tx][ty + i]);
}

// GEMM1: h = A @ W1 + b1 via bf16 MFMA, fused masked BN stats.
// Block 128Mx256N, BK=64, 512 thr = 8 waves of 64x64. Register-prefetch
// pipeline: tile k+1 loads issue BEFORE the MFMA section of tile k.
// Hout layout per 128x256 chunk (chunk = by*2+bx): [nl (256)][m (128)].
__global__ __launch_bounds__(512, 4) void gemm1_mfma(
    const float* __restrict__ A, const unsigned short* __restrict__ W1t,
    const float* __restrict__ b1, const int* __restrict__ mask,
    unsigned short* __restrict__ Hout,
    float* __restrict__ gsum, float* __restrict__ gsq)
{
  __shared__ unsigned short As[BM * LDK];   // [m][k]
  __shared__ unsigned short Bs[BN2 * LDK];  // [n][k]
  __shared__ float csum[BN2];
  __shared__ float csq[BN2];

  const int t = threadIdx.x;
  const int bx = blockIdx.x;   // N: 0..1
  const int by = blockIdx.y;   // M: 0..511
  const int bm0 = by * BM;
  const int bn0 = bx * BN2;

  const int w = t >> 6;
  const int lane = t & 63;
  const int wm0 = (w >> 2) * 64;
  const int wn0 = (w & 3) * 64;
  const int l15 = lane & 15;
  const int quad = lane >> 4;

  // staging maps
  const int am = t >> 2;           // 0..127
  const int ak = (t & 3) * 16;     // 0/16/32/48
  const int bn = t >> 1;           // 0..255
  const int bk = (t & 1) * 32;     // 0/32

  const float* Ap = A + (size_t)(bm0 + am) * Dn + ak;
  const unsigned short* Bp = W1t + (size_t)(bn0 + bn) * Dn + bk;

  f32x4 acc[4][4];
#pragma unroll
  for (int i = 0; i < 4; i++)
#pragma unroll
    for (int j = 0; j < 4; j++) acc[i][j] = (f32x4){0.f, 0.f, 0.f, 0.f};

  // prologue: prefetch tile 0
  float4 ra0 = *(const float4*)(Ap);
  float4 ra1 = *(const float4*)(Ap + 4);
  float4 ra2 = *(const float4*)(Ap + 8);
  float4 ra3 = *(const float4*)(Ap + 12);
  uint4 rb0 = *(const uint4*)(Bp);
  uint4 rb1 = *(const uint4*)(Bp + 8);
  uint4 rb2 = *(const uint4*)(Bp + 16);
  uint4 rb3 = *(const uint4*)(Bp + 24);

  for (int k0 = 0; k0 < Dn; k0 += BK) {
    __syncthreads();  // prior iter's LDS reads done
    uint4 p0, p1;
    p0.x = (unsigned int)f2bf(ra0.x) | ((unsigned int)f2bf(ra0.y) << 16);
    p0.y = (unsigned int)f2bf(ra0.z) | ((unsigned int)f2bf(ra0.w) << 16);
    p0.z = (unsigned int)f2bf(ra1.x) | ((unsigned int)f2bf(ra1.y) << 16);
    p0.w = (unsigned int)f2bf(ra1.z) | ((unsigned int)f2bf(ra1.w) << 16);
    p1.x = (unsigned int)f2bf(ra2.x) | ((unsigned int)f2bf(ra2.y) << 16);
    p1.y = (unsigned int)f2bf(ra2.z) | ((unsigned int)f2bf(ra2.w) << 16);
    p1.z = (unsigned int)f2bf(ra3.x) | ((unsigned int)f2bf(ra3.y) << 16);
    p1.w = (unsigned int)f2bf(ra3.z) | ((unsigned int)f2bf(ra3.w) << 16);
    *(uint4*)&As[am * LDK + ak] = p0;
    *(uint4*)&As[am * LDK + ak + 8] = p1;
    *(uint4*)&Bs[bn * LDK + bk] = rb0;
    *(uint4*)&Bs[bn * LDK + bk + 8] = rb1;
    *(uint4*)&Bs[bn * LDK + bk + 16] = rb2;
    *(uint4*)&Bs[bn * LDK + bk + 24] = rb3;
    __syncthreads();

    if (k0 + BK < Dn) {  // prefetch next tile (overlaps MFMA below)
      ra0 = *(const float4*)(Ap + k0 + BK);
      ra1 = *(const float4*)(Ap + k0 + BK + 4);
      ra2 = *(const float4*)(Ap + k0 + BK + 8);
      ra3 = *(const float4*)(Ap + k0 + BK + 12);
      rb0 = *(const uint4*)(Bp + k0 + BK);
      rb1 = *(const uint4*)(Bp + k0 + BK + 8);
      rb2 = *(const uint4*)(Bp + k0 + BK + 16);
      rb3 = *(const uint4*)(Bp + k0 + BK + 24);
    }

#pragma unroll
    for (int s = 0; s < 2; s++) {
      bf16x8 af[4], bf[4];
#pragma unroll
      for (int mt = 0; mt < 4; mt++)
        af[mt] = *(const bf16x8*)&As[(wm0 + mt * 16 + l15) * LDK + s * 32 + quad * 8];
#pragma unroll
      for (int nt = 0; nt < 4; nt++)
        bf[nt] = *(const bf16x8*)&Bs[(wn0 + nt * 16 + l15) * LDK + s * 32 + quad * 8];
#pragma unroll
      for (int mt = 0; mt < 4; mt++)
#pragma unroll
        for (int nt = 0; nt < 4; nt++)
          acc[mt][nt] = __builtin_amdgcn_mfma_f32_16x16x32_bf16(
              af[mt], bf[nt], acc[mt][nt], 0, 0, 0);
    }
  }

  // ---- epilogue: bias, masked stats, channel-major bf16 store ----
  if (t < BN2) { csum[t] = 0.f; csq[t] = 0.f; }
  __syncthreads();

  float mk[4][4];
#pragma unroll
  for (int mt = 0; mt < 4; mt++) {
    int4 mv = *(const int4*)(mask + bm0 + wm0 + mt * 16 + quad * 4);
    mk[mt][0] = (float)mv.x; mk[mt][1] = (float)mv.y;
    mk[mt][2] = (float)mv.z; mk[mt][3] = (float)mv.w;
  }

  const size_t cbase = ((size_t)(by * 2 + bx)) * 32768;
#pragma unroll
  for (int nt = 0; nt < 4; nt++) {
    const int nl = wn0 + nt * 16 + l15;
    const float bias = b1[bn0 + nl];
    float ps = 0.f, pq = 0.f;
#pragma unroll
    for (int mt = 0; mt < 4; mt++) {
      ushort4 st;
      float v0 = acc[mt][nt][0] + bias;
      float v1 = acc[mt][nt][1] + bias;
      float v2 = acc[mt][nt][2] + bias;
      float v3 = acc[mt][nt][3] + bias;
      ps += v0 * mk[mt][0] + v1 * mk[mt][1] + v2 * mk[mt][2] + v3 * mk[mt][3];
      pq += v0 * v0 * mk[mt][0] + v1 * v1 * mk[mt][1] +
            v2 * v2 * mk[mt][2] + v3 * v3 * mk[mt][3];
      st.x = f2bf(v0); st.y = f2bf(v1); st.z = f2bf(v2); st.w = f2bf(v3);
      // [nl][m] layout: m = wm0 + mt*16 + quad*4 + r
      *(ushort4*)&Hout[cbase + (size_t)nl * 128 + wm0 + mt * 16 + quad * 4] = st;
    }
    atomicAdd(&csum[nl], ps);
    atomicAdd(&csq[nl], pq);
  }

  __syncthreads();
  if (t < BN2) {
    atomicAdd(&gsum[bn0 + t], csum[t]);
    atomicAdd(&gsq[bn0 + t], csq[t]);
  }
}

__global__ void finalize_kernel(float* __restrict__ ws,
                                const float* __restrict__ gamma,
                                const float* __restrict__ beta) {
  __shared__ float nv;
  int t = threadIdx.x;  // 512
  if (t == 0) {
    float s = 0.f;
    for (int i = 0; i < Bn; i++) s += ws[OFF_CNT + i];
    nv = fmaxf(s, 1.f);
  }
  __syncthreads();
  float inv = 1.f / nv;
  float m = ws[OFF_S1 + t] * inv;
  float var = ws[OFF_S2 + t] * inv - m * m;
  float istd = rsqrtf(fmaxf(var, 0.f) + EPSC);
  float sc = istd * gamma[t];
  ws[OFF_SC + t] = sc;
  ws[OFF_SH + t] = beta[t] - m * sc;
}

// BN + ReLU + masked pool. One block per channel c (512 blocks); no atomics.
// Wave w handles by = 16j + s*4 + w; lanes cover the 128 m's (ushort2 each).
// acc[j] per-lane registers (j = batch 0..31), shuffle-reduced at the end.
__global__ __launch_bounds__(256) void bnpool_kernel(
    const unsigned short* __restrict__ Hbuf, const int* __restrict__ mask,
    const float* __restrict__ sc, const float* __restrict__ sh,
    float* __restrict__ pooled)
{
  __shared__ float part[4][32];
  const int t = threadIdx.x;
  const int c = blockIdx.x;       // 0..511
  const int bx = c >> 8, cl = c & 255;
  const int w4 = t >> 6, lane = t & 63;
  const float scv = sc[c], shv = sh[c];

  float acc[32];
#pragma unroll
  for (int j = 0; j < 32; j++) acc[j] = 0.f;

#pragma unroll 4
  for (int jj = 0; jj < 32; jj++) {
#pragma unroll
    for (int s = 0; s < 4; s++) {
      const int by = jj * 16 + s * 4 + w4;
      const size_t base = ((size_t)(by * 2 + bx)) * 32768 + (size_t)cl * 128;
      unsigned int hv = *(const unsigned int*)(Hbuf + base + lane * 2);
      int2 mv = *(const int2*)(mask + by * 128 + lane * 2);
      float v0 = fmaxf(fmaf(bf2f((unsigned short)hv), scv, shv), 0.f);
      float v1 = fmaxf(fmaf(bf2f((unsigned short)(hv >> 16)), scv, shv), 0.f);
      acc[jj] += v0 * (float)mv.x + v1 * (float)mv.y;
    }
  }

#pragma unroll
  for (int j = 0; j < 32; j++) {
    float v = acc[j];
#pragma unroll
    for (int off = 32; off > 0; off >>= 1) v += __shfl_down(v, off);
    if (lane == 0) part[w4][j] = v;
  }
  __syncthreads();
  if (t < 32)
    pooled[t * Hn + c] = part[0][t] + part[1][t] + part[2][t] + part[3][t];
}

// out[b][c] = (PH[b]/max(cnt,1)) @ W2[:,c] + b2[c]*(cnt/max(cnt,1))
__global__ __launch_bounds__(128) void final_kernel(
    const float* __restrict__ pooledh, const float* __restrict__ cnt,
    const float* __restrict__ W2, const float* __restrict__ b2,
    float* __restrict__ out)
{
  __shared__ float pr[Hn];
  int b = blockIdx.x >> 2;
  int cc = blockIdx.x & 3;
  int t = threadIdx.x;
  float nb = cnt[b];
  float inv = 1.f / fmaxf(nb, 1.f);
#pragma unroll
  for (int i = 0; i < 4; i++)
    pr[t + i * 128] = pooledh[b * Hn + t + i * 128] * inv;
  __syncthreads();
  int c = cc * 128 + t;
  float a0 = 0.f, a1 = 0.f, a2 = 0.f, a3 = 0.f;
  for (int i = 0; i < Hn; i += 4) {
    a0 = fmaf(pr[i],     W2[(size_t)i * Hn + c],           a0);
    a1 = fmaf(pr[i + 1], W2[(size_t)(i + 1) * Hn + c],     a1);
    a2 = fmaf(pr[i + 2], W2[(size_t)(i + 2) * Hn + c],     a2);
    a3 = fmaf(pr[i + 3], W2[(size_t)(i + 3) * Hn + c],     a3);
  }
  out[b * Hn + c] = (a0 + a1) + (a2 + a3) + b2[c] * (nb * inv);
}

extern "C" void kernel_launch(void* const* d_in, const int* in_sizes, int n_in,
                              void* d_out, int out_size, void* d_ws, size_t ws_size,
                              hipStream_t stream) {
  const float* hidden = (const float*)d_in[0];
  const int*   mask   = (const int*)d_in[1];
  const float* W1     = (const float*)d_in[2];
  const float* b1     = (const float*)d_in[3];
  const float* gamma  = (const float*)d_in[4];
  const float* beta   = (const float*)d_in[5];
  const float* W2     = (const float*)d_in[6];
  const float* b2     = (const float*)d_in[7];
  float* out = (float*)d_out;
  float* ws  = (float*)d_ws;
  unsigned short* W1t  = (unsigned short*)((char*)d_ws + OFF_W1T_BYTES);
  unsigned short* Hbuf = (unsigned short*)((char*)d_ws + OFF_H_BYTES);

  zero_kernel<<<(ZERO_N + 255) / 256, 256, 0, stream>>>(ws, ZERO_N);
  count_kernel<<<Bn, 256, 0, stream>>>(mask, ws + OFF_CNT);
  transpose_w1<<<dim3(Dn / 32, Hn / 32), 256, 0, stream>>>(W1, W1t);
  gemm1_mfma<<<dim3(Hn / BN2, Mn / BM), 512, 0, stream>>>(
      hidden, W1t, b1, mask, Hbuf, ws + OFF_S1, ws + OFF_S2);
  finalize_kernel<<<1, Hn, 0, stream>>>(ws, gamma, beta);
  bnpool_kernel<<<Hn, 256, 0, stream>>>(
      Hbuf, mask, ws + OFF_SC, ws + OFF_SH, ws + OFF_PH);
  final_kernel<<<Bn * 4, 128, 0, stream>>>(ws + OFF_PH, ws + OFF_CNT, W2, b2, out);
}